// Round 7
// baseline (6183.191 us; speedup 1.0000x reference)
//
#include <hip/hip_runtime.h>
#include <hip/hip_cooperative_groups.h>

namespace cg = cooperative_groups;

#define NT 499    // T-1 sequential steps
#define NB 64     // batch (= wave size, lane = b)
#define NN 512    // region width
#define ND 100    // input dim
#define NO 10     // output dim
#define NWAVE 16  // waves per WG (1024 threads) -> 4 waves/SIMD
#define KW 32     // k-slice width per wave (16*32 = 512)
#define NWG 256

// workspace layout (floats)
#define XT_SZ   (NT * ND * NB)     // XT[t][d][b] = X[t+1][b][d]
#define RBUF_SZ (2 * NN * NB)      // double-buffered rT[buf][n][b]
#define XT_OFF  0
#define RM_OFF  (XT_OFF + XT_SZ)
#define RP_OFF  (RM_OFF + RBUF_SZ)
#define RS_OFF  (RP_OFF + RBUF_SZ)
#define FLAG_OFF (RS_OFF + RBUF_SZ)   // word 0 = barrier counter

// sc write-through store: publishes r to the coherence point directly, so NO
// release fence (buffer_wbl2 drain) is needed anywhere (R2-R6 proven:
// __syncthreads' vmcnt(0) drains these before the barrier add issues).
__device__ __forceinline__ void st_cg(float* p, float v) {
  __hip_atomic_store(p, v, __ATOMIC_RELAXED, __HIP_MEMORY_SCOPE_AGENT);
}

// Transpose X[t+1][b][d] -> XT[t][d][b] so the main loop's lane=b loads coalesce.
__global__ void xpose_kernel(const float* __restrict__ X, float* __restrict__ XT) {
  __shared__ float tile[NB * ND];
  const int t = blockIdx.x;
  const float* src = X + (size_t)(t + 1) * NB * ND;
  for (int i = threadIdx.x; i < NB * ND; i += blockDim.x) tile[i] = src[i];
  __syncthreads();
  float* dst = XT + (size_t)t * ND * NB;
  for (int i = threadIdx.x; i < NB * ND; i += blockDim.x) {
    const int d = i >> 6, b = i & 63;
    dst[i] = tile[b * ND + d];
  }
}

// Persistent cooperative kernel: 256 WGs x 1024 threads (16 waves = 4/SIMD).
// R7 delta vs R6: main phase preloads ALL 96 r values into VGPRs (fully
// unrolled, constant-indexed arrays) so the post-invalidate cold misses
// expose ONE latency bubble instead of ~6 (VGPR 48 was the limiter; we run
// exactly 4 waves/EU so __launch_bounds__(1024,4) allows 128 VGPRs).
__global__ void __launch_bounds__(1024, 4)
rnn_kernel(const float* __restrict__ XT,
           float* __restrict__ r_m1, float* __restrict__ r_pmd, float* __restrict__ r_s1,
           const float* __restrict__ W_rec_m1, const float* __restrict__ W_rec_pmd,
           const float* __restrict__ W_rec_s1,
           const float* __restrict__ b_m1, const float* __restrict__ b_pmd,
           const float* __restrict__ b_s1,
           const float* __restrict__ W_pmd_m1, const float* __restrict__ W_s1_m1,
           const float* __restrict__ W_m1_pmd, const float* __restrict__ W_in_pmd,
           const float* __restrict__ W_in_s1, const float* __restrict__ W_out,
           float* __restrict__ out,
           unsigned* __restrict__ flags, unsigned* __restrict__ gen)
{
  (void)gen;
  unsigned* cnt = flags;   // single barrier counter, monotonic over steps
  const int g    = blockIdx.x;
  const int wave = __builtin_amdgcn_readfirstlane((int)threadIdx.x >> 6);
  const int lane = (int)threadIdx.x & 63;
  const int n0 = 2 * g, n1 = 2 * g + 1;
  const int k0 = __builtin_amdgcn_readfirstlane(wave * KW);
  const int d0 = __builtin_amdgcn_readfirstlane(wave * 7);   // 16*7=112 covers ND=100
  int dlen = ND - d0; dlen = dlen < 0 ? 0 : (dlen > 7 ? 7 : dlen);
  const bool has_out = (g < NO);

  __shared__ float red[NWAVE][7][64];   // 28 KB; slot 6 = window-phase ao partials

  // ws is poisoned before every launch: zero r slot 0 and the counter.
  for (int i = g * (int)blockDim.x + (int)threadIdx.x; i < NN * NB;
       i += (int)(gridDim.x * blockDim.x)) {
    r_m1[i] = 0.f; r_pmd[i] = 0.f; r_s1[i] = 0.f;
  }
  if (g == 0 && threadIdx.x == 0) *cnt = 0u;

  // wave-uniform weight row pointers -> scalar loads (K$-resident)
  const float* wrm0 = W_rec_m1 + (size_t)n0 * NN + k0;
  const float* wrm1 = W_rec_m1 + (size_t)n1 * NN + k0;
  const float* wmp0 = W_m1_pmd + (size_t)n0 * NN + k0;
  const float* wmp1 = W_m1_pmd + (size_t)n1 * NN + k0;
  const float* wpm0 = W_pmd_m1 + (size_t)n0 * NN + k0;
  const float* wpm1 = W_pmd_m1 + (size_t)n1 * NN + k0;
  const float* wrp0 = W_rec_pmd + (size_t)n0 * NN + k0;
  const float* wrp1 = W_rec_pmd + (size_t)n1 * NN + k0;
  const float* wsm0 = W_s1_m1 + (size_t)n0 * NN + k0;
  const float* wsm1 = W_s1_m1 + (size_t)n1 * NN + k0;
  const float* wrs0 = W_rec_s1 + (size_t)n0 * NN + k0;
  const float* wrs1 = W_rec_s1 + (size_t)n1 * NN + k0;
  const float* wip0 = W_in_pmd + (size_t)n0 * ND + d0;
  const float* wip1 = W_in_pmd + (size_t)n1 * ND + d0;
  const float* wis0 = W_in_s1 + (size_t)n0 * ND + d0;
  const float* wis1 = W_in_s1 + (size_t)n1 * ND + d0;
  const float* wo   = W_out + (size_t)(has_out ? g : 0) * NN + k0;

  // publish role: wave j<6 owns x-state target j; wave 6 reduces out
  float* pubBase = nullptr; float bP = 0.f;
  if (wave == 0)      { pubBase = r_m1  + n0 * NB; bP = b_m1[n0]; }
  else if (wave == 1) { pubBase = r_m1  + n1 * NB; bP = b_m1[n1]; }
  else if (wave == 2) { pubBase = r_pmd + n0 * NB; bP = b_pmd[n0]; }
  else if (wave == 3) { pubBase = r_pmd + n1 * NB; bP = b_pmd[n1]; }
  else if (wave == 4) { pubBase = r_s1  + n0 * NB; bP = b_s1[n0]; }
  else if (wave == 5) { pubBase = r_s1  + n1 * NB; bP = b_s1[n1]; }
  float xP = 0.f;   // per-wave persistent x-state (lane = b)

  // X-part accumulators for the upcoming step (computed during barrier wait)
  float apX0 = 0.f, apX1 = 0.f, asX0 = 0.f, asX1 = 0.f;
  {
    const float* xt = XT + d0 * NB + lane;   // ti = 0
    for (int d = 0; d < dlen; ++d) {
      const float v = xt[d * NB];
      apX0 = fmaf(v, wip0[d], apX0);
      apX1 = fmaf(v, wip1[d], apX1);
      asX0 = fmaf(v, wis0[d], asX0);
      asX1 = fmaf(v, wis1[d], asX1);
    }
  }

  // one-time heavyweight sync to order init (cnt/r zeroing) grid-wide
  cg::this_grid().sync();

  for (int ti = 0; ti < NT; ++ti) {
    const int cur = ti & 1, nxt = cur ^ 1;
    const float* rm = r_m1 + cur * NN * NB + k0 * NB + lane;
    const float* rp = r_pmd + cur * NN * NB + k0 * NB + lane;
    const float* rs = r_s1 + cur * NN * NB + k0 * NB + lane;

    // ---- preload ALL r operands into VGPRs (one deep load cluster: the
    // post-invalidate cold-miss latency is exposed once, not per-batch) ----
    float vm[KW], vp[KW], vs[KW];
    #pragma unroll
    for (int k = 0; k < KW; ++k) vm[k] = rm[k * NB];
    #pragma unroll
    for (int k = 0; k < KW; ++k) vp[k] = rp[k * NB];
    #pragma unroll
    for (int k = 0; k < KW; ++k) vs[k] = rs[k * NB];

    float am0 = 0.f, am1 = 0.f;
    float ap0 = apX0, ap1 = apX1, as0 = asX0, as1 = asX1;

    // pure FMA burn (weights via scalar K$-resident loads)
    #pragma unroll
    for (int k = 0; k < KW; ++k) {
      am0 = fmaf(vm[k], wrm0[k], am0);
      am1 = fmaf(vm[k], wrm1[k], am1);
      ap0 = fmaf(vm[k], wmp0[k], ap0);
      ap1 = fmaf(vm[k], wmp1[k], ap1);
    }
    #pragma unroll
    for (int k = 0; k < KW; ++k) {
      am0 = fmaf(vp[k], wpm0[k], am0);
      am1 = fmaf(vp[k], wpm1[k], am1);
      ap0 = fmaf(vp[k], wrp0[k], ap0);
      ap1 = fmaf(vp[k], wrp1[k], ap1);
    }
    #pragma unroll
    for (int k = 0; k < KW; ++k) {
      am0 = fmaf(vs[k], wsm0[k], am0);
      am1 = fmaf(vs[k], wsm1[k], am1);
      as0 = fmaf(vs[k], wrs0[k], as0);
      as1 = fmaf(vs[k], wrs1[k], as1);
    }

    red[wave][0][lane] = am0; red[wave][1][lane] = am1;
    red[wave][2][lane] = ap0; red[wave][3][lane] = ap1;
    red[wave][4][lane] = as0; red[wave][5][lane] = as1;
    __syncthreads();

    // publish: wave j<6 reduces its x-target; wave 6 reduces the red[.][6]
    // written during iteration ti-1's window = r_{ti-2}·W_out = out[ti-2].
    if (wave < 6) {
      float s = red[0][wave][lane];
      #pragma unroll
      for (int w = 1; w < NWAVE; ++w) s += red[w][wave][lane];
      xP = 0.9f * xP + 0.1f * (s + bP);
      st_cg(pubBase + nxt * NN * NB + lane, tanhf(xP));
    } else if (wave == 6 && has_out && ti >= 2) {
      float s = red[0][6][lane];
      #pragma unroll
      for (int w = 1; w < NWAVE; ++w) s += red[w][6][lane];
      out[(size_t)(ti - 2) * (NB * NO) + lane * NO + g] = s;
    }

    // ---- single-hop counter barrier. __syncthreads drains the sc r-stores
    // (vmcnt(0) before s_barrier), so the fetch_add is ordered behind them. ----
    __syncthreads();
    const unsigned tgtc = (unsigned)(ti + 1) * (unsigned)NWG;
    if (threadIdx.x == 0) {
      __hip_atomic_fetch_add(cnt, 1u, __ATOMIC_RELAXED, __HIP_MEMORY_SCOPE_AGENT);
    }

    // ---- barrier-wait window: work that only needs CURRENT-step data ----
    // (a) X-part of step ti+1 (static XT/W_in)
    apX0 = 0.f; apX1 = 0.f; asX0 = 0.f; asX1 = 0.f;
    if (ti + 1 < NT) {
      const float* xt = XT + (size_t)(ti + 1) * ND * NB + d0 * NB + lane;
      for (int d = 0; d < dlen; ++d) {
        const float v = xt[d * NB];
        apX0 = fmaf(v, wip0[d], apX0);
        apX1 = fmaf(v, wip1[d], apX1);
        asX0 = fmaf(v, wis0[d], asX0);
        asX1 = fmaf(v, wis1[d], asX1);
      }
    }
    // (b) W_out pass over the register-held r_m1 slice = r_{ti-1}.
    if (has_out) {
      float ao = 0.f;
      #pragma unroll
      for (int k = 0; k < KW; ++k) ao = fmaf(vm[k], wo[k], ao);
      red[wave][6][lane] = ao;
    }

    if (threadIdx.x == 0) {
      while (__hip_atomic_load(cnt, __ATOMIC_RELAXED,
                               __HIP_MEMORY_SCOPE_AGENT) < tgtc)
        __builtin_amdgcn_s_sleep(1);
      __builtin_amdgcn_fence(__ATOMIC_ACQUIRE, "agent");   // acquire-only inv
    }
    __syncthreads();
  }

  // epilogue (per-WG; has_out uniform within WG so barriers are safe):
  if (has_out) {
    // out[NT-2] from the last window's red[.][6] (= r_{NT-2}·W_out)
    if (wave == 6) {
      float s = red[0][6][lane];
      #pragma unroll
      for (int w = 1; w < NWAVE; ++w) s += red[w][6][lane];
      out[(size_t)(NT - 2) * (NB * NO) + lane * NO + g] = s;
    }
    __syncthreads();
    // out[NT-1] from the final r (buffer NT&1), fresh after the last acquire
    const float* rm = r_m1 + (NT & 1) * NN * NB + k0 * NB + lane;
    float ao = 0.f;
    #pragma unroll
    for (int k = 0; k < KW; ++k) ao = fmaf(rm[k * NB], wo[k], ao);
    red[wave][6][lane] = ao;
    __syncthreads();
    if (wave == 6) {
      float t = red[0][6][lane];
      #pragma unroll
      for (int w = 1; w < NWAVE; ++w) t += red[w][6][lane];
      out[(size_t)(NT - 1) * (NB * NO) + lane * NO + g] = t;
    }
  }
}

extern "C" void kernel_launch(void* const* d_in, const int* in_sizes, int n_in,
                              void* d_out, int out_size, void* d_ws, size_t ws_size,
                              hipStream_t stream) {
  (void)in_sizes; (void)n_in; (void)out_size; (void)ws_size;
  const float* X         = (const float*)d_in[0];
  const float* W_rec_m1  = (const float*)d_in[1];
  const float* W_rec_pmd = (const float*)d_in[2];
  const float* W_rec_s1  = (const float*)d_in[3];
  const float* b_m1      = (const float*)d_in[4];
  const float* b_pmd     = (const float*)d_in[5];
  const float* b_s1      = (const float*)d_in[6];
  const float* W_pmd_m1  = (const float*)d_in[7];
  const float* W_s1_m1   = (const float*)d_in[8];
  const float* W_m1_pmd  = (const float*)d_in[9];
  const float* W_in_pmd  = (const float*)d_in[10];
  const float* W_in_s1   = (const float*)d_in[11];
  const float* W_out     = (const float*)d_in[12];
  float* out = (float*)d_out;

  float* wsf = (float*)d_ws;
  const float* XT = wsf + XT_OFF;
  float* XTw   = wsf + XT_OFF;
  float* r_m1  = wsf + RM_OFF;
  float* r_pmd = wsf + RP_OFF;
  float* r_s1  = wsf + RS_OFF;
  unsigned* flags = (unsigned*)(wsf + FLAG_OFF);
  unsigned* gen   = flags + 256 * 16;

  xpose_kernel<<<NT, 256, 0, stream>>>(X, XTw);

  void* args[19];
  args[0]  = (void*)&XT;
  args[1]  = (void*)&r_m1;  args[2]  = (void*)&r_pmd; args[3]  = (void*)&r_s1;
  args[4]  = (void*)&W_rec_m1; args[5] = (void*)&W_rec_pmd; args[6] = (void*)&W_rec_s1;
  args[7]  = (void*)&b_m1;  args[8]  = (void*)&b_pmd; args[9]  = (void*)&b_s1;
  args[10] = (void*)&W_pmd_m1; args[11] = (void*)&W_s1_m1; args[12] = (void*)&W_m1_pmd;
  args[13] = (void*)&W_in_pmd; args[14] = (void*)&W_in_s1; args[15] = (void*)&W_out;
  args[16] = (void*)&out;
  args[17] = (void*)&flags;
  args[18] = (void*)&gen;
  hipLaunchCooperativeKernel((const void*)rnn_kernel, dim3(NWG), dim3(1024), args, 0, stream);
}

// Round 8
// 5969.298 us; speedup vs baseline: 1.0358x; 1.0358x over previous
//
#include <hip/hip_runtime.h>
#include <hip/hip_cooperative_groups.h>

namespace cg = cooperative_groups;

#define NT 499    // T-1 sequential steps
#define NB 64     // batch (= wave size, lane = b)
#define NN 512    // region width
#define ND 100    // input dim
#define NO 10     // output dim
#define NWAVE 16  // waves per WG (1024 threads) -> 4 waves/SIMD
#define KW 32     // k-slice width per wave (16*32 = 512)
#define NWG 256

// workspace layout (floats) — offsets unchanged; r buffers now hold packed
// bf16x2 (u32) and use half the space within their old slots.
#define XT_SZ   (NT * ND * NB)     // XT[t][d][b] = X[t+1][b][d]
#define RBUF_SZ (2 * NN * NB)
#define XT_OFF  0
#define RM_OFF  (XT_OFF + XT_SZ)
#define RP_OFF  (RM_OFF + RBUF_SZ)
#define RS_OFF  (RP_OFF + RBUF_SZ)
#define FLAG_OFF (RS_OFF + RBUF_SZ)   // word 0 = barrier counter
#define RPK_STRIDE ((NN / 2) * NB)    // u32 per packed r buffer

// sc write-through store: publishes r to the coherence point directly, so NO
// release fence (buffer_wbl2 drain) is needed anywhere (R2-R7 proven:
// __syncthreads' vmcnt(0) drains these before the barrier add issues).
__device__ __forceinline__ void st_cg_u(unsigned* p, unsigned v) {
  __hip_atomic_store(p, v, __ATOMIC_RELAXED, __HIP_MEMORY_SCOPE_AGENT);
}

// f32 -> bf16 with round-to-nearest-even (tanh output: finite, |x|<=1)
__device__ __forceinline__ unsigned f2bf(float f) {
  unsigned u = __float_as_uint(f);
  return (u + 0x7fffu + ((u >> 16) & 1u)) >> 16;
}

// Transpose X[t+1][b][d] -> XT[t][d][b] so the main loop's lane=b loads coalesce.
__global__ void xpose_kernel(const float* __restrict__ X, float* __restrict__ XT) {
  __shared__ float tile[NB * ND];
  const int t = blockIdx.x;
  const float* src = X + (size_t)(t + 1) * NB * ND;
  for (int i = threadIdx.x; i < NB * ND; i += blockDim.x) tile[i] = src[i];
  __syncthreads();
  float* dst = XT + (size_t)t * ND * NB;
  for (int i = threadIdx.x; i < NB * ND; i += blockDim.x) {
    const int d = i >> 6, b = i & 63;
    dst[i] = tile[b * ND + d];
  }
}

// Persistent cooperative kernel: 256 WGs x 1024 threads (16 waves = 4/SIMD).
// R8 delta vs R7: r transport is PACKED BF16x2. Halves per-WG vector-load
// count (96->48: L1 miss processing is per-CU serialized and was the
// TLP-invisible binder), halves L2/LLC refill bytes and store-drain depth.
// Publishers: wave j<3 owns region j's column PAIR (n0,n1): reduces both,
// keeps two x-states, packs tanh pair into one u32 sc store. Wave 3: out.
__global__ void __launch_bounds__(1024, 4)
rnn_kernel(const float* __restrict__ XT,
           unsigned* __restrict__ rmPK, unsigned* __restrict__ rpPK,
           unsigned* __restrict__ rsPK,
           const float* __restrict__ W_rec_m1, const float* __restrict__ W_rec_pmd,
           const float* __restrict__ W_rec_s1,
           const float* __restrict__ b_m1, const float* __restrict__ b_pmd,
           const float* __restrict__ b_s1,
           const float* __restrict__ W_pmd_m1, const float* __restrict__ W_s1_m1,
           const float* __restrict__ W_m1_pmd, const float* __restrict__ W_in_pmd,
           const float* __restrict__ W_in_s1, const float* __restrict__ W_out,
           float* __restrict__ out,
           unsigned* __restrict__ flags, unsigned* __restrict__ gen)
{
  (void)gen;
  unsigned* cnt = flags;   // single barrier counter, monotonic over steps
  const int g    = blockIdx.x;
  const int wave = __builtin_amdgcn_readfirstlane((int)threadIdx.x >> 6);
  const int lane = (int)threadIdx.x & 63;
  const int n0 = 2 * g, n1 = 2 * g + 1;
  const int k0 = __builtin_amdgcn_readfirstlane(wave * KW);
  const int m0 = __builtin_amdgcn_readfirstlane(wave * (KW / 2));  // packed idx
  const int d0 = __builtin_amdgcn_readfirstlane(wave * 7);   // 16*7=112 covers ND=100
  int dlen = ND - d0; dlen = dlen < 0 ? 0 : (dlen > 7 ? 7 : dlen);
  const bool has_out = (g < NO);

  __shared__ float red[NWAVE][7][64];   // 28 KB; slot 6 = window-phase ao partials

  // ws is poisoned before every launch: zero packed r slot 0 and the counter.
  for (int i = g * (int)blockDim.x + (int)threadIdx.x; i < RPK_STRIDE;
       i += (int)(gridDim.x * blockDim.x)) {
    rmPK[i] = 0u; rpPK[i] = 0u; rsPK[i] = 0u;
  }
  if (g == 0 && threadIdx.x == 0) *cnt = 0u;

  // wave-uniform weight row pointers -> scalar loads (K$-resident)
  const float* wrm0 = W_rec_m1 + (size_t)n0 * NN + k0;
  const float* wrm1 = W_rec_m1 + (size_t)n1 * NN + k0;
  const float* wmp0 = W_m1_pmd + (size_t)n0 * NN + k0;
  const float* wmp1 = W_m1_pmd + (size_t)n1 * NN + k0;
  const float* wpm0 = W_pmd_m1 + (size_t)n0 * NN + k0;
  const float* wpm1 = W_pmd_m1 + (size_t)n1 * NN + k0;
  const float* wrp0 = W_rec_pmd + (size_t)n0 * NN + k0;
  const float* wrp1 = W_rec_pmd + (size_t)n1 * NN + k0;
  const float* wsm0 = W_s1_m1 + (size_t)n0 * NN + k0;
  const float* wsm1 = W_s1_m1 + (size_t)n1 * NN + k0;
  const float* wrs0 = W_rec_s1 + (size_t)n0 * NN + k0;
  const float* wrs1 = W_rec_s1 + (size_t)n1 * NN + k0;
  const float* wip0 = W_in_pmd + (size_t)n0 * ND + d0;
  const float* wip1 = W_in_pmd + (size_t)n1 * ND + d0;
  const float* wis0 = W_in_s1 + (size_t)n0 * ND + d0;
  const float* wis1 = W_in_s1 + (size_t)n1 * ND + d0;
  const float* wo   = W_out + (size_t)(has_out ? g : 0) * NN + k0;

  // publish role: wave j<3 owns region j's pair; wave 3 reduces out
  unsigned* pubPK = nullptr; float bP0 = 0.f, bP1 = 0.f;
  if (wave == 0)      { pubPK = rmPK; bP0 = b_m1[n0];  bP1 = b_m1[n1]; }
  else if (wave == 1) { pubPK = rpPK; bP0 = b_pmd[n0]; bP1 = b_pmd[n1]; }
  else if (wave == 2) { pubPK = rsPK; bP0 = b_s1[n0];  bP1 = b_s1[n1]; }
  float xP0 = 0.f, xP1 = 0.f;   // per-wave persistent x-state pair (lane = b)

  // X-part accumulators for the upcoming step (computed during barrier wait)
  float apX0 = 0.f, apX1 = 0.f, asX0 = 0.f, asX1 = 0.f;
  {
    const float* xt = XT + d0 * NB + lane;   // ti = 0
    for (int d = 0; d < dlen; ++d) {
      const float v = xt[d * NB];
      apX0 = fmaf(v, wip0[d], apX0);
      apX1 = fmaf(v, wip1[d], apX1);
      asX0 = fmaf(v, wis0[d], asX0);
      asX1 = fmaf(v, wis1[d], asX1);
    }
  }

  // one-time heavyweight sync to order init (cnt/r zeroing) grid-wide
  cg::this_grid().sync();

  for (int ti = 0; ti < NT; ++ti) {
    const int cur = ti & 1, nxt = cur ^ 1;
    const unsigned* rmP = rmPK + cur * RPK_STRIDE + m0 * NB + lane;
    const unsigned* rpP = rpPK + cur * RPK_STRIDE + m0 * NB + lane;
    const unsigned* rsP = rsPK + cur * RPK_STRIDE + m0 * NB + lane;

    // ---- load 48 packed dwords, unpack to 96 floats (bf16: u<<16 = lo col,
    // u&0xffff0000 = hi col; even n in low half matches pack below) ----
    float vm[KW], vp[KW], vs[KW];
    #pragma unroll
    for (int k2 = 0; k2 < KW / 2; ++k2) {
      const unsigned u = rmP[k2 * NB];
      vm[2 * k2]     = __uint_as_float(u << 16);
      vm[2 * k2 + 1] = __uint_as_float(u & 0xffff0000u);
    }
    #pragma unroll
    for (int k2 = 0; k2 < KW / 2; ++k2) {
      const unsigned u = rpP[k2 * NB];
      vp[2 * k2]     = __uint_as_float(u << 16);
      vp[2 * k2 + 1] = __uint_as_float(u & 0xffff0000u);
    }
    #pragma unroll
    for (int k2 = 0; k2 < KW / 2; ++k2) {
      const unsigned u = rsP[k2 * NB];
      vs[2 * k2]     = __uint_as_float(u << 16);
      vs[2 * k2 + 1] = __uint_as_float(u & 0xffff0000u);
    }

    float am0 = 0.f, am1 = 0.f;
    float ap0 = apX0, ap1 = apX1, as0 = asX0, as1 = asX1;

    // pure FMA burn (weights via scalar K$-resident loads)
    #pragma unroll
    for (int k = 0; k < KW; ++k) {
      am0 = fmaf(vm[k], wrm0[k], am0);
      am1 = fmaf(vm[k], wrm1[k], am1);
      ap0 = fmaf(vm[k], wmp0[k], ap0);
      ap1 = fmaf(vm[k], wmp1[k], ap1);
    }
    #pragma unroll
    for (int k = 0; k < KW; ++k) {
      am0 = fmaf(vp[k], wpm0[k], am0);
      am1 = fmaf(vp[k], wpm1[k], am1);
      ap0 = fmaf(vp[k], wrp0[k], ap0);
      ap1 = fmaf(vp[k], wrp1[k], ap1);
    }
    #pragma unroll
    for (int k = 0; k < KW; ++k) {
      am0 = fmaf(vs[k], wsm0[k], am0);
      am1 = fmaf(vs[k], wsm1[k], am1);
      as0 = fmaf(vs[k], wrs0[k], as0);
      as1 = fmaf(vs[k], wrs1[k], as1);
    }

    red[wave][0][lane] = am0; red[wave][1][lane] = am1;
    red[wave][2][lane] = ap0; red[wave][3][lane] = ap1;
    red[wave][4][lane] = as0; red[wave][5][lane] = as1;
    __syncthreads();

    // publish: wave j<3 reduces its region pair, leaky+tanh both columns,
    // packs bf16x2, ONE sc store. Wave 3 stores out[ti-2] from the red[.][6]
    // written during iteration ti-1's window (= r_{ti-2}·W_out).
    if (wave < 3) {
      float s0 = red[0][2 * wave][lane], s1 = red[0][2 * wave + 1][lane];
      #pragma unroll
      for (int w = 1; w < NWAVE; ++w) {
        s0 += red[w][2 * wave][lane];
        s1 += red[w][2 * wave + 1][lane];
      }
      xP0 = 0.9f * xP0 + 0.1f * (s0 + bP0);
      xP1 = 0.9f * xP1 + 0.1f * (s1 + bP1);
      const unsigned pk = f2bf(tanhf(xP0)) | (f2bf(tanhf(xP1)) << 16);
      st_cg_u(pubPK + nxt * RPK_STRIDE + g * NB + lane, pk);
    } else if (wave == 3 && has_out && ti >= 2) {
      float s = red[0][6][lane];
      #pragma unroll
      for (int w = 1; w < NWAVE; ++w) s += red[w][6][lane];
      out[(size_t)(ti - 2) * (NB * NO) + lane * NO + g] = s;
    }

    // ---- single-hop counter barrier. __syncthreads drains the sc r-stores
    // (vmcnt(0) before s_barrier), so the fetch_add is ordered behind them. ----
    __syncthreads();
    const unsigned tgtc = (unsigned)(ti + 1) * (unsigned)NWG;
    if (threadIdx.x == 0) {
      __hip_atomic_fetch_add(cnt, 1u, __ATOMIC_RELAXED, __HIP_MEMORY_SCOPE_AGENT);
    }

    // ---- barrier-wait window: work that only needs CURRENT-step data ----
    // (a) X-part of step ti+1 (static XT/W_in)
    apX0 = 0.f; apX1 = 0.f; asX0 = 0.f; asX1 = 0.f;
    if (ti + 1 < NT) {
      const float* xt = XT + (size_t)(ti + 1) * ND * NB + d0 * NB + lane;
      for (int d = 0; d < dlen; ++d) {
        const float v = xt[d * NB];
        apX0 = fmaf(v, wip0[d], apX0);
        apX1 = fmaf(v, wip1[d], apX1);
        asX0 = fmaf(v, wis0[d], asX0);
        asX1 = fmaf(v, wis1[d], asX1);
      }
    }
    // (b) W_out pass over the register-held r_m1 slice = r_{ti-1}.
    if (has_out) {
      float ao = 0.f;
      #pragma unroll
      for (int k = 0; k < KW; ++k) ao = fmaf(vm[k], wo[k], ao);
      red[wave][6][lane] = ao;
    }

    if (threadIdx.x == 0) {
      while (__hip_atomic_load(cnt, __ATOMIC_RELAXED,
                               __HIP_MEMORY_SCOPE_AGENT) < tgtc)
        __builtin_amdgcn_s_sleep(1);
      __builtin_amdgcn_fence(__ATOMIC_ACQUIRE, "agent");   // acquire-only inv
    }
    __syncthreads();
  }

  // epilogue (per-WG; has_out uniform within WG so barriers are safe):
  if (has_out) {
    // out[NT-2] from the last window's red[.][6] (= r_{NT-2}·W_out)
    if (wave == 3) {
      float s = red[0][6][lane];
      #pragma unroll
      for (int w = 1; w < NWAVE; ++w) s += red[w][6][lane];
      out[(size_t)(NT - 2) * (NB * NO) + lane * NO + g] = s;
    }
    __syncthreads();
    // out[NT-1] from the final r (buffer NT&1), fresh after the last acquire
    const unsigned* rmP = rmPK + (NT & 1) * RPK_STRIDE + m0 * NB + lane;
    float ao = 0.f;
    #pragma unroll
    for (int k2 = 0; k2 < KW / 2; ++k2) {
      const unsigned u = rmP[k2 * NB];
      ao = fmaf(__uint_as_float(u << 16),        wo[2 * k2],     ao);
      ao = fmaf(__uint_as_float(u & 0xffff0000u), wo[2 * k2 + 1], ao);
    }
    red[wave][6][lane] = ao;
    __syncthreads();
    if (wave == 3) {
      float t = red[0][6][lane];
      #pragma unroll
      for (int w = 1; w < NWAVE; ++w) t += red[w][6][lane];
      out[(size_t)(NT - 1) * (NB * NO) + lane * NO + g] = t;
    }
  }
}

extern "C" void kernel_launch(void* const* d_in, const int* in_sizes, int n_in,
                              void* d_out, int out_size, void* d_ws, size_t ws_size,
                              hipStream_t stream) {
  (void)in_sizes; (void)n_in; (void)out_size; (void)ws_size;
  const float* X         = (const float*)d_in[0];
  const float* W_rec_m1  = (const float*)d_in[1];
  const float* W_rec_pmd = (const float*)d_in[2];
  const float* W_rec_s1  = (const float*)d_in[3];
  const float* b_m1      = (const float*)d_in[4];
  const float* b_pmd     = (const float*)d_in[5];
  const float* b_s1      = (const float*)d_in[6];
  const float* W_pmd_m1  = (const float*)d_in[7];
  const float* W_s1_m1   = (const float*)d_in[8];
  const float* W_m1_pmd  = (const float*)d_in[9];
  const float* W_in_pmd  = (const float*)d_in[10];
  const float* W_in_s1   = (const float*)d_in[11];
  const float* W_out     = (const float*)d_in[12];
  float* out = (float*)d_out;

  float* wsf = (float*)d_ws;
  const float* XT = wsf + XT_OFF;
  float* XTw   = wsf + XT_OFF;
  unsigned* rmPK = (unsigned*)(wsf + RM_OFF);
  unsigned* rpPK = (unsigned*)(wsf + RP_OFF);
  unsigned* rsPK = (unsigned*)(wsf + RS_OFF);
  unsigned* flags = (unsigned*)(wsf + FLAG_OFF);
  unsigned* gen   = flags + 256 * 16;

  xpose_kernel<<<NT, 256, 0, stream>>>(X, XTw);

  void* args[19];
  args[0]  = (void*)&XT;
  args[1]  = (void*)&rmPK;  args[2]  = (void*)&rpPK; args[3]  = (void*)&rsPK;
  args[4]  = (void*)&W_rec_m1; args[5] = (void*)&W_rec_pmd; args[6] = (void*)&W_rec_s1;
  args[7]  = (void*)&b_m1;  args[8]  = (void*)&b_pmd; args[9]  = (void*)&b_s1;
  args[10] = (void*)&W_pmd_m1; args[11] = (void*)&W_s1_m1; args[12] = (void*)&W_m1_pmd;
  args[13] = (void*)&W_in_pmd; args[14] = (void*)&W_in_s1; args[15] = (void*)&W_out;
  args[16] = (void*)&out;
  args[17] = (void*)&flags;
  args[18] = (void*)&gen;
  hipLaunchCooperativeKernel((const void*)rnn_kernel, dim3(NWG), dim3(1024), args, 0, stream);
}

// Round 9
// 4624.605 us; speedup vs baseline: 1.3370x; 1.2908x over previous
//
#include <hip/hip_runtime.h>
#include <hip/hip_cooperative_groups.h>

namespace cg = cooperative_groups;

#define NT 499    // T-1 sequential steps
#define NB 64     // batch (= wave size, lane = b)
#define NN 512    // region width
#define ND 100    // input dim
#define NO 10     // output dim
#define NWAVE 16  // waves per WG (1024 threads) -> 4 waves/SIMD
#define KW 32     // k-slice width per wave (16*32 = 512)
#define NWG 256

// workspace layout (floats)
#define XT_SZ   (NT * ND * NB)     // XT[t][d][b] = X[t+1][b][d]
#define RBUF_SZ (2 * NN * NB)
#define XT_OFF  0
#define RM_OFF  (XT_OFF + XT_SZ)
#define RP_OFF  (RM_OFF + RBUF_SZ)
#define RS_OFF  (RP_OFF + RBUF_SZ)
#define FLAG_OFF (RS_OFF + RBUF_SZ)   // word 0 = barrier counter
#define RPK_STRIDE ((NN / 2) * NB)    // u32 per packed r buffer

// sc write-through store: publishes r to the coherence point (R2-R8 proven).
__device__ __forceinline__ void st_cg_u(unsigned* p, unsigned v) {
  __hip_atomic_store(p, v, __ATOMIC_RELAXED, __HIP_MEMORY_SCOPE_AGENT);
}

// LLC-direct coherent load: bypasses (never allocates) L1/L2, reads the
// coherence point. Same semantics __hip_atomic_load(AGENT) had in R2 (proven
// correct end-to-end there), but hand-clustered: 48 issued back-to-back, ONE
// manual vmcnt(0). This removes the need for ANY acquire fence in the loop.
#define LD_SC(dst, addr) \
  asm volatile("global_load_dword %0, %1, off sc0 sc1" : "=v"(dst) : "v"(addr))

// f32 -> bf16 round-to-nearest-even
__device__ __forceinline__ unsigned f2bf(float f) {
  unsigned u = __float_as_uint(f);
  return (u + 0x7fffu + ((u >> 16) & 1u)) >> 16;
}

// Transpose X[t+1][b][d] -> XT[t][d][b] so the main loop's lane=b loads coalesce.
__global__ void xpose_kernel(const float* __restrict__ X, float* __restrict__ XT) {
  __shared__ float tile[NB * ND];
  const int t = blockIdx.x;
  const float* src = X + (size_t)(t + 1) * NB * ND;
  for (int i = threadIdx.x; i < NB * ND; i += blockDim.x) tile[i] = src[i];
  __syncthreads();
  float* dst = XT + (size_t)t * ND * NB;
  for (int i = threadIdx.x; i < NB * ND; i += blockDim.x) {
    const int d = i >> 6, b = i & 63;
    dst[i] = tile[b * ND + d];
  }
}

// Persistent cooperative kernel: 256 WGs x 1024 threads (16 waves = 4/SIMD).
// R9 delta vs R8: r loads are LLC-direct (sc0 sc1) asm, hand-clustered with
// one vmcnt(0); the per-step acquire fence (L1+L2 invalidate walk — the
// suspected multi-us residual, cf. R0->R3's wbl2 removal) is DELETED.
// Weights/XT now stay cached across all 499 steps with no invalidation ever.
__global__ void __launch_bounds__(1024, 4)
rnn_kernel(const float* __restrict__ XT,
           unsigned* __restrict__ rmPK, unsigned* __restrict__ rpPK,
           unsigned* __restrict__ rsPK,
           const float* __restrict__ W_rec_m1, const float* __restrict__ W_rec_pmd,
           const float* __restrict__ W_rec_s1,
           const float* __restrict__ b_m1, const float* __restrict__ b_pmd,
           const float* __restrict__ b_s1,
           const float* __restrict__ W_pmd_m1, const float* __restrict__ W_s1_m1,
           const float* __restrict__ W_m1_pmd, const float* __restrict__ W_in_pmd,
           const float* __restrict__ W_in_s1, const float* __restrict__ W_out,
           float* __restrict__ out,
           unsigned* __restrict__ flags, unsigned* __restrict__ gen)
{
  (void)gen;
  unsigned* cnt = flags;   // single barrier counter, monotonic over steps
  const int g    = blockIdx.x;
  const int wave = __builtin_amdgcn_readfirstlane((int)threadIdx.x >> 6);
  const int lane = (int)threadIdx.x & 63;
  const int n0 = 2 * g, n1 = 2 * g + 1;
  const int k0 = __builtin_amdgcn_readfirstlane(wave * KW);
  const int m0 = __builtin_amdgcn_readfirstlane(wave * (KW / 2));  // packed idx
  const int d0 = __builtin_amdgcn_readfirstlane(wave * 7);   // 16*7=112 covers ND=100
  int dlen = ND - d0; dlen = dlen < 0 ? 0 : (dlen > 7 ? 7 : dlen);
  const bool has_out = (g < NO);

  __shared__ float red[NWAVE][7][64];   // 28 KB; slot 6 = window-phase ao partials

  // ws is poisoned before every launch: zero packed r slot 0 and the counter.
  // (grid.sync below performs the release that makes these LLC-visible.)
  for (int i = g * (int)blockDim.x + (int)threadIdx.x; i < RPK_STRIDE;
       i += (int)(gridDim.x * blockDim.x)) {
    rmPK[i] = 0u; rpPK[i] = 0u; rsPK[i] = 0u;
  }
  if (g == 0 && threadIdx.x == 0) *cnt = 0u;

  // wave-uniform weight row pointers -> scalar loads (K$-resident, and now
  // never invalidated across the whole run)
  const float* wrm0 = W_rec_m1 + (size_t)n0 * NN + k0;
  const float* wrm1 = W_rec_m1 + (size_t)n1 * NN + k0;
  const float* wmp0 = W_m1_pmd + (size_t)n0 * NN + k0;
  const float* wmp1 = W_m1_pmd + (size_t)n1 * NN + k0;
  const float* wpm0 = W_pmd_m1 + (size_t)n0 * NN + k0;
  const float* wpm1 = W_pmd_m1 + (size_t)n1 * NN + k0;
  const float* wrp0 = W_rec_pmd + (size_t)n0 * NN + k0;
  const float* wrp1 = W_rec_pmd + (size_t)n1 * NN + k0;
  const float* wsm0 = W_s1_m1 + (size_t)n0 * NN + k0;
  const float* wsm1 = W_s1_m1 + (size_t)n1 * NN + k0;
  const float* wrs0 = W_rec_s1 + (size_t)n0 * NN + k0;
  const float* wrs1 = W_rec_s1 + (size_t)n1 * NN + k0;
  const float* wip0 = W_in_pmd + (size_t)n0 * ND + d0;
  const float* wip1 = W_in_pmd + (size_t)n1 * ND + d0;
  const float* wis0 = W_in_s1 + (size_t)n0 * ND + d0;
  const float* wis1 = W_in_s1 + (size_t)n1 * ND + d0;
  const float* wo   = W_out + (size_t)(has_out ? g : 0) * NN + k0;

  // publish role: wave j<3 owns region j's column pair; wave 3 reduces out
  unsigned* pubPK = nullptr; float bP0 = 0.f, bP1 = 0.f;
  if (wave == 0)      { pubPK = rmPK; bP0 = b_m1[n0];  bP1 = b_m1[n1]; }
  else if (wave == 1) { pubPK = rpPK; bP0 = b_pmd[n0]; bP1 = b_pmd[n1]; }
  else if (wave == 2) { pubPK = rsPK; bP0 = b_s1[n0];  bP1 = b_s1[n1]; }
  float xP0 = 0.f, xP1 = 0.f;   // per-wave persistent x-state pair (lane = b)

  // X-part accumulators for the upcoming step (computed during barrier wait)
  float apX0 = 0.f, apX1 = 0.f, asX0 = 0.f, asX1 = 0.f;
  {
    const float* xt = XT + d0 * NB + lane;   // ti = 0
    for (int d = 0; d < dlen; ++d) {
      const float v = xt[d * NB];
      apX0 = fmaf(v, wip0[d], apX0);
      apX1 = fmaf(v, wip1[d], apX1);
      asX0 = fmaf(v, wis0[d], asX0);
      asX1 = fmaf(v, wis1[d], asX1);
    }
  }

  // one-time heavyweight sync to order init (cnt/r zeroing) grid-wide
  cg::this_grid().sync();

  for (int ti = 0; ti < NT; ++ti) {
    const int cur = ti & 1, nxt = cur ^ 1;
    const unsigned* rmP = rmPK + cur * RPK_STRIDE + m0 * NB + lane;
    const unsigned* rpP = rpPK + cur * RPK_STRIDE + m0 * NB + lane;
    const unsigned* rsP = rsPK + cur * RPK_STRIDE + m0 * NB + lane;

    // ---- 48 LLC-direct loads issued back-to-back, ONE vmcnt(0) ----
    unsigned um[KW / 2], uP[KW / 2], uS[KW / 2];
    #pragma unroll
    for (int k2 = 0; k2 < KW / 2; ++k2) LD_SC(um[k2], rmP + k2 * NB);
    #pragma unroll
    for (int k2 = 0; k2 < KW / 2; ++k2) LD_SC(uP[k2], rpP + k2 * NB);
    #pragma unroll
    for (int k2 = 0; k2 < KW / 2; ++k2) LD_SC(uS[k2], rsP + k2 * NB);
    asm volatile("s_waitcnt vmcnt(0)" ::: "memory");
    __builtin_amdgcn_sched_barrier(0);   // rule #18: pin consumers after wait

    // unpack r_m1 to registers (kept live for the W_out window pass)
    float vm[KW];
    #pragma unroll
    for (int k2 = 0; k2 < KW / 2; ++k2) {
      vm[2 * k2]     = __uint_as_float(um[k2] << 16);
      vm[2 * k2 + 1] = __uint_as_float(um[k2] & 0xffff0000u);
    }

    float am0 = 0.f, am1 = 0.f;
    float ap0 = apX0, ap1 = apX1, as0 = asX0, as1 = asX1;

    #pragma unroll
    for (int k = 0; k < KW; ++k) {
      am0 = fmaf(vm[k], wrm0[k], am0);
      am1 = fmaf(vm[k], wrm1[k], am1);
      ap0 = fmaf(vm[k], wmp0[k], ap0);
      ap1 = fmaf(vm[k], wmp1[k], ap1);
    }
    // r_pmd / r_s1 consumed inline from packed form (keeps VGPR peak low)
    #pragma unroll
    for (int k2 = 0; k2 < KW / 2; ++k2) {
      const float f0 = __uint_as_float(uP[k2] << 16);
      const float f1 = __uint_as_float(uP[k2] & 0xffff0000u);
      am0 = fmaf(f0, wpm0[2 * k2], am0);     am1 = fmaf(f0, wpm1[2 * k2], am1);
      ap0 = fmaf(f0, wrp0[2 * k2], ap0);     ap1 = fmaf(f0, wrp1[2 * k2], ap1);
      am0 = fmaf(f1, wpm0[2 * k2 + 1], am0); am1 = fmaf(f1, wpm1[2 * k2 + 1], am1);
      ap0 = fmaf(f1, wrp0[2 * k2 + 1], ap0); ap1 = fmaf(f1, wrp1[2 * k2 + 1], ap1);
    }
    #pragma unroll
    for (int k2 = 0; k2 < KW / 2; ++k2) {
      const float f0 = __uint_as_float(uS[k2] << 16);
      const float f1 = __uint_as_float(uS[k2] & 0xffff0000u);
      am0 = fmaf(f0, wsm0[2 * k2], am0);     am1 = fmaf(f0, wsm1[2 * k2], am1);
      as0 = fmaf(f0, wrs0[2 * k2], as0);     as1 = fmaf(f0, wrs1[2 * k2], as1);
      am0 = fmaf(f1, wsm0[2 * k2 + 1], am0); am1 = fmaf(f1, wsm1[2 * k2 + 1], am1);
      as0 = fmaf(f1, wrs0[2 * k2 + 1], as0); as1 = fmaf(f1, wrs1[2 * k2 + 1], as1);
    }

    red[wave][0][lane] = am0; red[wave][1][lane] = am1;
    red[wave][2][lane] = ap0; red[wave][3][lane] = ap1;
    red[wave][4][lane] = as0; red[wave][5][lane] = as1;
    __syncthreads();

    // publish: wave j<3 reduces its region pair -> leaky+tanh -> bf16x2 pack
    // -> ONE sc store. Wave 3 stores out[ti-2] from prior window's red[.][6].
    if (wave < 3) {
      float s0 = red[0][2 * wave][lane], s1 = red[0][2 * wave + 1][lane];
      #pragma unroll
      for (int w = 1; w < NWAVE; ++w) {
        s0 += red[w][2 * wave][lane];
        s1 += red[w][2 * wave + 1][lane];
      }
      xP0 = 0.9f * xP0 + 0.1f * (s0 + bP0);
      xP1 = 0.9f * xP1 + 0.1f * (s1 + bP1);
      const unsigned pk = f2bf(tanhf(xP0)) | (f2bf(tanhf(xP1)) << 16);
      st_cg_u(pubPK + nxt * RPK_STRIDE + g * NB + lane, pk);
    } else if (wave == 3 && has_out && ti >= 2) {
      float s = red[0][6][lane];
      #pragma unroll
      for (int w = 1; w < NWAVE; ++w) s += red[w][6][lane];
      out[(size_t)(ti - 2) * (NB * NO) + lane * NO + g] = s;
    }

    // ---- single-hop counter barrier; sc stores drained by syncthreads ----
    __syncthreads();
    const unsigned tgtc = (unsigned)(ti + 1) * (unsigned)NWG;
    if (threadIdx.x == 0) {
      __hip_atomic_fetch_add(cnt, 1u, __ATOMIC_RELAXED, __HIP_MEMORY_SCOPE_AGENT);
    }

    // ---- barrier-wait window ----
    apX0 = 0.f; apX1 = 0.f; asX0 = 0.f; asX1 = 0.f;
    if (ti + 1 < NT) {
      const float* xt = XT + (size_t)(ti + 1) * ND * NB + d0 * NB + lane;
      for (int d = 0; d < dlen; ++d) {
        const float v = xt[d * NB];
        apX0 = fmaf(v, wip0[d], apX0);
        apX1 = fmaf(v, wip1[d], apX1);
        asX0 = fmaf(v, wis0[d], asX0);
        asX1 = fmaf(v, wis1[d], asX1);
      }
    }
    if (has_out) {
      float ao = 0.f;
      #pragma unroll
      for (int k = 0; k < KW; ++k) ao = fmaf(vm[k], wo[k], ao);
      red[wave][6][lane] = ao;
    }

    if (threadIdx.x == 0) {
      while (__hip_atomic_load(cnt, __ATOMIC_RELAXED,
                               __HIP_MEMORY_SCOPE_AGENT) < tgtc)
        __builtin_amdgcn_s_sleep(1);
      // NO acquire fence: consumers read r via LLC-direct sc loads, which
      // never hit (never allocate) L1/L2 lines — nothing can be stale.
    }
    __syncthreads();
  }

  // epilogue (per-WG; has_out uniform within WG so barriers are safe):
  if (has_out) {
    if (wave == 3) {
      float s = red[0][6][lane];
      #pragma unroll
      for (int w = 1; w < NWAVE; ++w) s += red[w][6][lane];
      out[(size_t)(NT - 2) * (NB * NO) + lane * NO + g] = s;
    }
    __syncthreads();
    // out[NT-1] from the final r (buffer NT&1) via LLC-direct loads
    const unsigned* rmP = rmPK + (NT & 1) * RPK_STRIDE + m0 * NB + lane;
    unsigned um[KW / 2];
    #pragma unroll
    for (int k2 = 0; k2 < KW / 2; ++k2) LD_SC(um[k2], rmP + k2 * NB);
    asm volatile("s_waitcnt vmcnt(0)" ::: "memory");
    __builtin_amdgcn_sched_barrier(0);
    float ao = 0.f;
    #pragma unroll
    for (int k2 = 0; k2 < KW / 2; ++k2) {
      ao = fmaf(__uint_as_float(um[k2] << 16),         wo[2 * k2],     ao);
      ao = fmaf(__uint_as_float(um[k2] & 0xffff0000u), wo[2 * k2 + 1], ao);
    }
    red[wave][6][lane] = ao;
    __syncthreads();
    if (wave == 3) {
      float t = red[0][6][lane];
      #pragma unroll
      for (int w = 1; w < NWAVE; ++w) t += red[w][6][lane];
      out[(size_t)(NT - 1) * (NB * NO) + lane * NO + g] = t;
    }
  }
}

extern "C" void kernel_launch(void* const* d_in, const int* in_sizes, int n_in,
                              void* d_out, int out_size, void* d_ws, size_t ws_size,
                              hipStream_t stream) {
  (void)in_sizes; (void)n_in; (void)out_size; (void)ws_size;
  const float* X         = (const float*)d_in[0];
  const float* W_rec_m1  = (const float*)d_in[1];
  const float* W_rec_pmd = (const float*)d_in[2];
  const float* W_rec_s1  = (const float*)d_in[3];
  const float* b_m1      = (const float*)d_in[4];
  const float* b_pmd     = (const float*)d_in[5];
  const float* b_s1      = (const float*)d_in[6];
  const float* W_pmd_m1  = (const float*)d_in[7];
  const float* W_s1_m1   = (const float*)d_in[8];
  const float* W_m1_pmd  = (const float*)d_in[9];
  const float* W_in_pmd  = (const float*)d_in[10];
  const float* W_in_s1   = (const float*)d_in[11];
  const float* W_out     = (const float*)d_in[12];
  float* out = (float*)d_out;

  float* wsf = (float*)d_ws;
  const float* XT = wsf + XT_OFF;
  float* XTw   = wsf + XT_OFF;
  unsigned* rmPK = (unsigned*)(wsf + RM_OFF);
  unsigned* rpPK = (unsigned*)(wsf + RP_OFF);
  unsigned* rsPK = (unsigned*)(wsf + RS_OFF);
  unsigned* flags = (unsigned*)(wsf + FLAG_OFF);
  unsigned* gen   = flags + 256 * 16;

  xpose_kernel<<<NT, 256, 0, stream>>>(X, XTw);

  void* args[19];
  args[0]  = (void*)&XT;
  args[1]  = (void*)&rmPK;  args[2]  = (void*)&rpPK; args[3]  = (void*)&rsPK;
  args[4]  = (void*)&W_rec_m1; args[5] = (void*)&W_rec_pmd; args[6] = (void*)&W_rec_s1;
  args[7]  = (void*)&b_m1;  args[8]  = (void*)&b_pmd; args[9]  = (void*)&b_s1;
  args[10] = (void*)&W_pmd_m1; args[11] = (void*)&W_s1_m1; args[12] = (void*)&W_m1_pmd;
  args[13] = (void*)&W_in_pmd; args[14] = (void*)&W_in_s1; args[15] = (void*)&W_out;
  args[16] = (void*)&out;
  args[17] = (void*)&flags;
  args[18] = (void*)&gen;
  hipLaunchCooperativeKernel((const void*)rnn_kernel, dim3(NWG), dim3(1024), args, 0, stream);
}

// Round 10
// 3640.939 us; speedup vs baseline: 1.6982x; 1.2702x over previous
//
#include <hip/hip_runtime.h>
#include <hip/hip_cooperative_groups.h>

namespace cg = cooperative_groups;

#define NT 499    // T-1 sequential steps
#define NB 64     // batch (= wave size, lane = b)
#define NN 512    // region width
#define ND 100    // input dim
#define NO 10     // output dim
#define NWAVE 16  // waves per WG (1024 threads) -> 4 waves/SIMD
#define KW 32     // k-slice width per wave (16*32 = 512)
#define NWG 256

typedef float f32x2 __attribute__((ext_vector_type(2)));

// workspace layout (floats)
#define XT_SZ   (NT * ND * NB)     // XT[t][d][b] = X[t+1][b][d]
#define RBUF_SZ (2 * NN * NB)
#define XT_OFF  0
#define RM_OFF  (XT_OFF + XT_SZ)
#define RP_OFF  (RM_OFF + RBUF_SZ)
#define RS_OFF  (RP_OFF + RBUF_SZ)
#define FLAG_OFF (RS_OFF + RBUF_SZ)   // [0]=root, [16*(i+1)]=leaf i (i<16)
#define RPK_STRIDE ((NN / 2) * NB)    // u32 per packed r buffer

// sc write-through store: publishes r to the coherence point (R2-R9 proven).
__device__ __forceinline__ void st_cg_u(unsigned* p, unsigned v) {
  __hip_atomic_store(p, v, __ATOMIC_RELAXED, __HIP_MEMORY_SCOPE_AGENT);
}

// LLC-direct coherent load, SGPR-base + imm-offset form: zero per-load VALU
// address math (R9's full-address form burned ~96 VALU/wave on v_add_co).
#define LD1(dst, base, voff, IMM) \
  asm volatile("global_load_dword %0, %1, %2 offset:" IMM " sc0 sc1" \
               : "=v"(dst) : "v"(voff), "s"(base))
#define LDR(u, base, voff) do { \
  LD1(u[0],  base, voff, "0");    LD1(u[1],  base, voff, "256");  \
  LD1(u[2],  base, voff, "512");  LD1(u[3],  base, voff, "768");  \
  LD1(u[4],  base, voff, "1024"); LD1(u[5],  base, voff, "1280"); \
  LD1(u[6],  base, voff, "1536"); LD1(u[7],  base, voff, "1792"); \
  LD1(u[8],  base, voff, "2048"); LD1(u[9],  base, voff, "2304"); \
  LD1(u[10], base, voff, "2560"); LD1(u[11], base, voff, "2816"); \
  LD1(u[12], base, voff, "3072"); LD1(u[13], base, voff, "3328"); \
  LD1(u[14], base, voff, "3584"); LD1(u[15], base, voff, "3840"); \
} while (0)

// legacy full-address LLC-direct load (epilogue only)
#define LD_SC(dst, addr) \
  asm volatile("global_load_dword %0, %1, off sc0 sc1" : "=v"(dst) : "v"(addr))

// packed dual-fp32 FMA: D.lo=S0.lo*S1.lo+S2.lo, D.hi likewise. Weight pair is
// the single allowed scalar operand (s_load_dwordx2 of two adjacent row elems).
#define PKFMA(acc, a, w) \
  asm("v_pk_fma_f32 %0, %1, %2, %0" : "+v"(acc) : "v"(a), "s"(w))

// f32 -> bf16 round-to-nearest-even
__device__ __forceinline__ unsigned f2bf(float f) {
  unsigned u = __float_as_uint(f);
  return (u + 0x7fffu + ((u >> 16) & 1u)) >> 16;
}

// Transpose X[t+1][b][d] -> XT[t][d][b] so the main loop's lane=b loads coalesce.
__global__ void xpose_kernel(const float* __restrict__ X, float* __restrict__ XT) {
  __shared__ float tile[NB * ND];
  const int t = blockIdx.x;
  const float* src = X + (size_t)(t + 1) * NB * ND;
  for (int i = threadIdx.x; i < NB * ND; i += blockDim.x) tile[i] = src[i];
  __syncthreads();
  float* dst = XT + (size_t)t * ND * NB;
  for (int i = threadIdx.x; i < NB * ND; i += blockDim.x) {
    const int d = i >> 6, b = i & 63;
    dst[i] = tile[b * ND + d];
  }
}

// Persistent cooperative kernel: 256 WGs x 1024 threads (16 waves = 4/SIMD).
// R10 deltas vs R9 (memory system proven non-binding; attack issue count +
// barrier serialization): (1) sc loads via SGPR-base + imm offsets (0 addr
// VALU); (2) v_pk_fma_f32 pairs over even/odd k — 384 fma -> 192 pk_fma,
// multiplier pair = the two halves of one packed bf16 dword; (3) two-level
// barrier tree: 16 leaf counters + root (256 -> 16+16 serialized RMWs).
__global__ void __launch_bounds__(1024, 4)
rnn_kernel(const float* __restrict__ XT,
           unsigned* __restrict__ rmPK, unsigned* __restrict__ rpPK,
           unsigned* __restrict__ rsPK,
           const float* __restrict__ W_rec_m1, const float* __restrict__ W_rec_pmd,
           const float* __restrict__ W_rec_s1,
           const float* __restrict__ b_m1, const float* __restrict__ b_pmd,
           const float* __restrict__ b_s1,
           const float* __restrict__ W_pmd_m1, const float* __restrict__ W_s1_m1,
           const float* __restrict__ W_m1_pmd, const float* __restrict__ W_in_pmd,
           const float* __restrict__ W_in_s1, const float* __restrict__ W_out,
           float* __restrict__ out,
           unsigned* __restrict__ flags, unsigned* __restrict__ gen)
{
  (void)gen;
  const int g    = blockIdx.x;
  const int grp  = g >> 4;                 // 16 groups of 16 WGs
  const int wave = __builtin_amdgcn_readfirstlane((int)threadIdx.x >> 6);
  const int lane = (int)threadIdx.x & 63;
  const int n0 = 2 * g, n1 = 2 * g + 1;
  const int k0 = __builtin_amdgcn_readfirstlane(wave * KW);
  const int m0 = __builtin_amdgcn_readfirstlane(wave * (KW / 2));  // packed idx
  const int d0 = __builtin_amdgcn_readfirstlane(wave * 7);
  int dlen = ND - d0; dlen = dlen < 0 ? 0 : (dlen > 7 ? 7 : dlen);
  const bool has_out = (g < NO);
  const unsigned voff = (unsigned)lane * 4u;   // shared per-lane byte offset

  __shared__ float red[NWAVE][7][64];   // 28 KB; slot 6 = window ao partials

  // ws is poisoned before every launch: zero packed r slot 0 + barrier words.
  for (int i = g * (int)blockDim.x + (int)threadIdx.x; i < RPK_STRIDE;
       i += (int)(gridDim.x * blockDim.x)) {
    rmPK[i] = 0u; rpPK[i] = 0u; rsPK[i] = 0u;
  }
  if (g <= 16 && threadIdx.x == 0) flags[g * 16] = 0u;   // root + 16 leaves

  // wave-uniform weight row pointers -> scalar loads (K$-resident, never
  // invalidated: no fences anywhere in the loop)
  const float* wrm0 = W_rec_m1 + (size_t)n0 * NN + k0;
  const float* wrm1 = W_rec_m1 + (size_t)n1 * NN + k0;
  const float* wmp0 = W_m1_pmd + (size_t)n0 * NN + k0;
  const float* wmp1 = W_m1_pmd + (size_t)n1 * NN + k0;
  const float* wpm0 = W_pmd_m1 + (size_t)n0 * NN + k0;
  const float* wpm1 = W_pmd_m1 + (size_t)n1 * NN + k0;
  const float* wrp0 = W_rec_pmd + (size_t)n0 * NN + k0;
  const float* wrp1 = W_rec_pmd + (size_t)n1 * NN + k0;
  const float* wsm0 = W_s1_m1 + (size_t)n0 * NN + k0;
  const float* wsm1 = W_s1_m1 + (size_t)n1 * NN + k0;
  const float* wrs0 = W_rec_s1 + (size_t)n0 * NN + k0;
  const float* wrs1 = W_rec_s1 + (size_t)n1 * NN + k0;
  const float* wip0 = W_in_pmd + (size_t)n0 * ND + d0;
  const float* wip1 = W_in_pmd + (size_t)n1 * ND + d0;
  const float* wis0 = W_in_s1 + (size_t)n0 * ND + d0;
  const float* wis1 = W_in_s1 + (size_t)n1 * ND + d0;
  const float* wo   = W_out + (size_t)(has_out ? g : 0) * NN + k0;

  // publish role: wave j<3 owns region j's column pair; wave 3 reduces out
  unsigned* pubPK = nullptr; float bP0 = 0.f, bP1 = 0.f;
  if (wave == 0)      { pubPK = rmPK; bP0 = b_m1[n0];  bP1 = b_m1[n1]; }
  else if (wave == 1) { pubPK = rpPK; bP0 = b_pmd[n0]; bP1 = b_pmd[n1]; }
  else if (wave == 2) { pubPK = rsPK; bP0 = b_s1[n0];  bP1 = b_s1[n1]; }
  float xP0 = 0.f, xP1 = 0.f;

  // X-part accumulators for the upcoming step (computed during barrier wait)
  float apX0 = 0.f, apX1 = 0.f, asX0 = 0.f, asX1 = 0.f;
  {
    const float* xt = XT + d0 * NB + lane;   // ti = 0
    for (int d = 0; d < dlen; ++d) {
      const float v = xt[d * NB];
      apX0 = fmaf(v, wip0[d], apX0);
      apX1 = fmaf(v, wip1[d], apX1);
      asX0 = fmaf(v, wis0[d], asX0);
      asX1 = fmaf(v, wis1[d], asX1);
    }
  }

  // one-time heavyweight sync to order init grid-wide
  cg::this_grid().sync();

  for (int ti = 0; ti < NT; ++ti) {
    const int cur = ti & 1, nxt = cur ^ 1;
    const unsigned* bM = rmPK + cur * RPK_STRIDE + m0 * NB;   // wave-uniform
    const unsigned* bP = rpPK + cur * RPK_STRIDE + m0 * NB;
    const unsigned* bS = rsPK + cur * RPK_STRIDE + m0 * NB;

    // ---- 48 LLC-direct loads, SGPR base + imm offsets, ONE vmcnt(0) ----
    unsigned um[16], uP[16], uS[16];
    LDR(um, bM, voff);
    LDR(uP, bP, voff);
    LDR(uS, bS, voff);
    asm volatile("s_waitcnt vmcnt(0)" ::: "memory");
    __builtin_amdgcn_sched_barrier(0);   // rule #18

    // unpack r_m1 into pair form (kept live for the W_out window pass);
    // vm2[j] = (r[2(m0+j)], r[2(m0+j)+1]) — matches weight pairs at +2j.
    f32x2 vm2[16];
    #pragma unroll
    for (int j = 0; j < 16; ++j) {
      vm2[j].x = __uint_as_float(um[j] << 16);
      vm2[j].y = __uint_as_float(um[j] & 0xffff0000u);
    }

    // packed accumulators: (even-k partial, odd-k partial)
    f32x2 am0p = {0.f, 0.f}, am1p = {0.f, 0.f};
    f32x2 ap0p = {apX0, 0.f}, ap1p = {apX1, 0.f};
    f32x2 as0p = {asX0, 0.f}, as1p = {asX1, 0.f};

    #pragma unroll
    for (int j = 0; j < 16; ++j) {
      const f32x2 w0 = *(const f32x2*)(wrm0 + 2 * j);
      const f32x2 w1 = *(const f32x2*)(wrm1 + 2 * j);
      const f32x2 w2 = *(const f32x2*)(wmp0 + 2 * j);
      const f32x2 w3 = *(const f32x2*)(wmp1 + 2 * j);
      PKFMA(am0p, vm2[j], w0);
      PKFMA(am1p, vm2[j], w1);
      PKFMA(ap0p, vm2[j], w2);
      PKFMA(ap1p, vm2[j], w3);
    }
    #pragma unroll
    for (int j = 0; j < 16; ++j) {
      f32x2 v; v.x = __uint_as_float(uP[j] << 16);
               v.y = __uint_as_float(uP[j] & 0xffff0000u);
      const f32x2 w0 = *(const f32x2*)(wpm0 + 2 * j);
      const f32x2 w1 = *(const f32x2*)(wpm1 + 2 * j);
      const f32x2 w2 = *(const f32x2*)(wrp0 + 2 * j);
      const f32x2 w3 = *(const f32x2*)(wrp1 + 2 * j);
      PKFMA(am0p, v, w0);
      PKFMA(am1p, v, w1);
      PKFMA(ap0p, v, w2);
      PKFMA(ap1p, v, w3);
    }
    #pragma unroll
    for (int j = 0; j < 16; ++j) {
      f32x2 v; v.x = __uint_as_float(uS[j] << 16);
               v.y = __uint_as_float(uS[j] & 0xffff0000u);
      const f32x2 w0 = *(const f32x2*)(wsm0 + 2 * j);
      const f32x2 w1 = *(const f32x2*)(wsm1 + 2 * j);
      const f32x2 w2 = *(const f32x2*)(wrs0 + 2 * j);
      const f32x2 w3 = *(const f32x2*)(wrs1 + 2 * j);
      PKFMA(am0p, v, w0);
      PKFMA(am1p, v, w1);
      PKFMA(as0p, v, w2);
      PKFMA(as1p, v, w3);
    }

    red[wave][0][lane] = am0p.x + am0p.y;
    red[wave][1][lane] = am1p.x + am1p.y;
    red[wave][2][lane] = ap0p.x + ap0p.y;
    red[wave][3][lane] = ap1p.x + ap1p.y;
    red[wave][4][lane] = as0p.x + as0p.y;
    red[wave][5][lane] = as1p.x + as1p.y;
    __syncthreads();

    // publish: wave j<3 reduces its region pair -> leaky+tanh -> bf16x2 pack
    // -> ONE sc store. Wave 3 stores out[ti-2] from prior window's red[.][6].
    if (wave < 3) {
      float s0 = red[0][2 * wave][lane], s1 = red[0][2 * wave + 1][lane];
      #pragma unroll
      for (int w = 1; w < NWAVE; ++w) {
        s0 += red[w][2 * wave][lane];
        s1 += red[w][2 * wave + 1][lane];
      }
      xP0 = 0.9f * xP0 + 0.1f * (s0 + bP0);
      xP1 = 0.9f * xP1 + 0.1f * (s1 + bP1);
      const unsigned pk = f2bf(tanhf(xP0)) | (f2bf(tanhf(xP1)) << 16);
      st_cg_u(pubPK + nxt * RPK_STRIDE + g * NB + lane, pk);
    } else if (wave == 3 && has_out && ti >= 2) {
      float s = red[0][6][lane];
      #pragma unroll
      for (int w = 1; w < NWAVE; ++w) s += red[w][6][lane];
      out[(size_t)(ti - 2) * (NB * NO) + lane * NO + g] = s;
    }

    // ---- two-level barrier tree. syncthreads drains the sc r-stores, so
    // leaf arrive is ordered behind them; last group-arriver promotes root.
    __syncthreads();
    const unsigned tgtc = (unsigned)(ti + 1) * 16u;
    if (threadIdx.x == 0) {
      const unsigned old = __hip_atomic_fetch_add(
          &flags[(grp + 1) * 16], 1u, __ATOMIC_RELAXED, __HIP_MEMORY_SCOPE_AGENT);
      if (old == tgtc - 1u) {   // 16th arriver of this group this step
        __hip_atomic_fetch_add(&flags[0], 1u, __ATOMIC_RELAXED,
                               __HIP_MEMORY_SCOPE_AGENT);
      }
    }

    // ---- barrier-wait window ----
    apX0 = 0.f; apX1 = 0.f; asX0 = 0.f; asX1 = 0.f;
    if (ti + 1 < NT) {
      const float* xt = XT + (size_t)(ti + 1) * ND * NB + d0 * NB + lane;
      for (int d = 0; d < dlen; ++d) {
        const float v = xt[d * NB];
        apX0 = fmaf(v, wip0[d], apX0);
        apX1 = fmaf(v, wip1[d], apX1);
        asX0 = fmaf(v, wis0[d], asX0);
        asX1 = fmaf(v, wis1[d], asX1);
      }
    }
    if (has_out) {
      f32x2 aop = {0.f, 0.f};
      #pragma unroll
      for (int j = 0; j < 16; ++j) {
        const f32x2 w = *(const f32x2*)(wo + 2 * j);
        PKFMA(aop, vm2[j], w);
      }
      red[wave][6][lane] = aop.x + aop.y;
    }

    if (threadIdx.x == 0) {
      while (__hip_atomic_load(&flags[0], __ATOMIC_RELAXED,
                               __HIP_MEMORY_SCOPE_AGENT) < tgtc)
        __builtin_amdgcn_s_sleep(1);
      // no acquire fence: r reads are LLC-direct (R9-proven)
    }
    __syncthreads();
  }

  // epilogue (per-WG; has_out uniform within WG so barriers are safe):
  if (has_out) {
    if (wave == 3) {
      float s = red[0][6][lane];
      #pragma unroll
      for (int w = 1; w < NWAVE; ++w) s += red[w][6][lane];
      out[(size_t)(NT - 2) * (NB * NO) + lane * NO + g] = s;
    }
    __syncthreads();
    const unsigned* rmP = rmPK + (NT & 1) * RPK_STRIDE + m0 * NB + lane;
    unsigned um[16];
    #pragma unroll
    for (int k2 = 0; k2 < 16; ++k2) LD_SC(um[k2], rmP + k2 * NB);
    asm volatile("s_waitcnt vmcnt(0)" ::: "memory");
    __builtin_amdgcn_sched_barrier(0);
    float ao = 0.f;
    #pragma unroll
    for (int k2 = 0; k2 < 16; ++k2) {
      ao = fmaf(__uint_as_float(um[k2] << 16),         wo[2 * k2],     ao);
      ao = fmaf(__uint_as_float(um[k2] & 0xffff0000u), wo[2 * k2 + 1], ao);
    }
    red[wave][6][lane] = ao;
    __syncthreads();
    if (wave == 3) {
      float t = red[0][6][lane];
      #pragma unroll
      for (int w = 1; w < NWAVE; ++w) t += red[w][6][lane];
      out[(size_t)(NT - 1) * (NB * NO) + lane * NO + g] = t;
    }
  }
}

extern "C" void kernel_launch(void* const* d_in, const int* in_sizes, int n_in,
                              void* d_out, int out_size, void* d_ws, size_t ws_size,
                              hipStream_t stream) {
  (void)in_sizes; (void)n_in; (void)out_size; (void)ws_size;
  const float* X         = (const float*)d_in[0];
  const float* W_rec_m1  = (const float*)d_in[1];
  const float* W_rec_pmd = (const float*)d_in[2];
  const float* W_rec_s1  = (const float*)d_in[3];
  const float* b_m1      = (const float*)d_in[4];
  const float* b_pmd     = (const float*)d_in[5];
  const float* b_s1      = (const float*)d_in[6];
  const float* W_pmd_m1  = (const float*)d_in[7];
  const float* W_s1_m1   = (const float*)d_in[8];
  const float* W_m1_pmd  = (const float*)d_in[9];
  const float* W_in_pmd  = (const float*)d_in[10];
  const float* W_in_s1   = (const float*)d_in[11];
  const float* W_out     = (const float*)d_in[12];
  float* out = (float*)d_out;

  float* wsf = (float*)d_ws;
  const float* XT = wsf + XT_OFF;
  float* XTw   = wsf + XT_OFF;
  unsigned* rmPK = (unsigned*)(wsf + RM_OFF);
  unsigned* rpPK = (unsigned*)(wsf + RP_OFF);
  unsigned* rsPK = (unsigned*)(wsf + RS_OFF);
  unsigned* flags = (unsigned*)(wsf + FLAG_OFF);
  unsigned* gen   = flags + 256 * 16;

  xpose_kernel<<<NT, 256, 0, stream>>>(X, XTw);

  void* args[19];
  args[0]  = (void*)&XT;
  args[1]  = (void*)&rmPK;  args[2]  = (void*)&rpPK; args[3]  = (void*)&rsPK;
  args[4]  = (void*)&W_rec_m1; args[5] = (void*)&W_rec_pmd; args[6] = (void*)&W_rec_s1;
  args[7]  = (void*)&b_m1;  args[8]  = (void*)&b_pmd; args[9]  = (void*)&b_s1;
  args[10] = (void*)&W_pmd_m1; args[11] = (void*)&W_s1_m1; args[12] = (void*)&W_m1_pmd;
  args[13] = (void*)&W_in_pmd; args[14] = (void*)&W_in_s1; args[15] = (void*)&W_out;
  args[16] = (void*)&out;
  args[17] = (void*)&flags;
  args[18] = (void*)&gen;
  hipLaunchCooperativeKernel((const void*)rnn_kernel, dim3(NWG), dim3(1024), args, 0, stream);
}

// Round 12
// 3262.586 us; speedup vs baseline: 1.8952x; 1.1160x over previous
//
#include <hip/hip_runtime.h>
#include <hip/hip_cooperative_groups.h>

namespace cg = cooperative_groups;

#define NT 499    // T-1 sequential steps
#define NB 64     // batch (= wave size, lane = b)
#define NN 512    // region width
#define ND 100    // input dim
#define NO 10     // output dim
#define NWAVE 16  // waves per WG (1024 threads) -> 4 waves/SIMD
#define KW 32     // k-slice width per wave (16*32 = 512)
#define NWG 256

// workspace layout (floats)
#define XT_SZ   (NT * ND * NB)     // XT[t][d][b] = X[t+1][b][d]
#define RBUF_SZ (2 * NN * NB)
#define XT_OFF  0
#define RM_OFF  (XT_OFF + XT_SZ)
#define RP_OFF  (RM_OFF + RBUF_SZ)
#define RS_OFF  (RP_OFF + RBUF_SZ)
#define FLAG_OFF (RS_OFF + RBUF_SZ)   // [0]=root, [16*(i+1)]=leaf i (i<16)
#define WPK_OFF  (FLAG_OFF + 8192)    // packed f16 weights (u32 k-pairs)
#define RPK_STRIDE ((NN / 2) * NB)    // u32 per packed r buffer
#define WMAT (NN * (NN / 2))          // 131072 u32 per packed 512x512 matrix

// sc write-through store: publishes r to the coherence point (R2-R10 proven).
__device__ __forceinline__ void st_cg_u(unsigned* p, unsigned v) {
  __hip_atomic_store(p, v, __ATOMIC_RELAXED, __HIP_MEMORY_SCOPE_AGENT);
}

// LLC-direct coherent load, SGPR-base + imm-offset form (R10-proven).
#define LD1(dst, base, voff, IMM) \
  asm volatile("global_load_dword %0, %1, %2 offset:" IMM " sc0 sc1" \
               : "=v"(dst) : "v"(voff), "s"(base))
#define LDR(u, base, voff) do { \
  LD1(u[0],  base, voff, "0");    LD1(u[1],  base, voff, "256");  \
  LD1(u[2],  base, voff, "512");  LD1(u[3],  base, voff, "768");  \
  LD1(u[4],  base, voff, "1024"); LD1(u[5],  base, voff, "1280"); \
  LD1(u[6],  base, voff, "1536"); LD1(u[7],  base, voff, "1792"); \
  LD1(u[8],  base, voff, "2048"); LD1(u[9],  base, voff, "2304"); \
  LD1(u[10], base, voff, "2560"); LD1(u[11], base, voff, "2816"); \
  LD1(u[12], base, voff, "3072"); LD1(u[13], base, voff, "3328"); \
  LD1(u[14], base, voff, "3584"); LD1(u[15], base, voff, "3840"); \
} while (0)

// legacy full-address LLC-direct load (epilogue only)
#define LD_SC(dst, addr) \
  asm volatile("global_load_dword %0, %1, off sc0 sc1" : "=v"(dst) : "v"(addr))

// f16-pair dot product with f32 accumulate: acc += a.lo*w.lo + a.hi*w.hi.
// R12: f16 replaces R11's bf16 — 4x less weight quant error (10 vs 7 mantissa
// bits), 8x less transport error; r in [-1,1] and |w|<0.25 fit f16 trivially.
#define DOT2(acc, a, w) \
  asm("v_dot2_f32_f16 %0, %1, %2, %0" : "+v"(acc) : "v"(a), "s"(w))

// f32 pair -> packed f16x2 (RTE via _Float16 cast)
__device__ __forceinline__ unsigned f2h2(float a, float b) {
  union { _Float16 h[2]; unsigned u; } cv;
  cv.h[0] = (_Float16)a; cv.h[1] = (_Float16)b;
  return cv.u;
}

// Transpose X[t+1][b][d] -> XT[t][d][b] so the main loop's lane=b loads coalesce.
__global__ void xpose_kernel(const float* __restrict__ X, float* __restrict__ XT) {
  __shared__ float tile[NB * ND];
  const int t = blockIdx.x;
  const float* src = X + (size_t)(t + 1) * NB * ND;
  for (int i = threadIdx.x; i < NB * ND; i += blockDim.x) tile[i] = src[i];
  __syncthreads();
  float* dst = XT + (size_t)t * ND * NB;
  for (int i = threadIdx.x; i < NB * ND; i += blockDim.x) {
    const int d = i >> 6, b = i & 63;
    dst[i] = tile[b * ND + d];
  }
}

// Pack 6 recurrent matrices + W_out into f16 k-pairs: wpk[row][k2] =
// f16(W[row][2k2]) | f16(W[row][2k2+1])<<16. One block per row.
__global__ void wpack_kernel(const float* __restrict__ W_rec_m1,
                             const float* __restrict__ W_m1_pmd,
                             const float* __restrict__ W_pmd_m1,
                             const float* __restrict__ W_rec_pmd,
                             const float* __restrict__ W_s1_m1,
                             const float* __restrict__ W_rec_s1,
                             const float* __restrict__ W_out,
                             unsigned* __restrict__ WPK) {
  const int idx = blockIdx.x, t = threadIdx.x;   // t = k2 in [0,256)
  const float* src; unsigned* dst;
  if (idx < 6 * NN) {
    const int mat = idx >> 9, row = idx & (NN - 1);
    const float* m[6] = {W_rec_m1, W_m1_pmd, W_pmd_m1, W_rec_pmd, W_s1_m1, W_rec_s1};
    src = m[mat] + (size_t)row * NN;
    dst = WPK + (size_t)mat * WMAT + (size_t)row * (NN / 2);
  } else {
    const int row = idx - 6 * NN;                // W_out rows 0..9
    src = W_out + (size_t)row * NN;
    dst = WPK + (size_t)6 * WMAT + (size_t)row * (NN / 2);
  }
  union { _Float16 h[2]; unsigned u; } cv;
  cv.h[0] = (_Float16)src[2 * t];
  cv.h[1] = (_Float16)src[2 * t + 1];
  dst[t] = cv.u;
}

// Persistent cooperative kernel: 256 WGs x 1024 threads (16 waves = 4/SIMD).
// R12 = R11 with bf16 -> IEEE f16 everywhere in transport+weights (R11 failed
// numerics by 6%: 0.0488 vs 0.0459; f16 cuts quant error 4-8x). Structure,
// barrier, LLC-direct loads identical to R11/R10.
__global__ void __launch_bounds__(1024, 4)
rnn_kernel(const float* __restrict__ XT,
           unsigned* __restrict__ rmPK, unsigned* __restrict__ rpPK,
           unsigned* __restrict__ rsPK,
           const unsigned* __restrict__ WPK,
           const float* __restrict__ b_m1, const float* __restrict__ b_pmd,
           const float* __restrict__ b_s1,
           const float* __restrict__ W_in_pmd, const float* __restrict__ W_in_s1,
           float* __restrict__ out,
           unsigned* __restrict__ flags)
{
  const int g    = blockIdx.x;
  const int grp  = g >> 4;                 // 16 groups of 16 WGs
  const int wave = __builtin_amdgcn_readfirstlane((int)threadIdx.x >> 6);
  const int lane = (int)threadIdx.x & 63;
  const int n0 = 2 * g, n1 = 2 * g + 1;
  const int m0 = __builtin_amdgcn_readfirstlane(wave * (KW / 2));  // packed idx
  const int d0 = __builtin_amdgcn_readfirstlane(wave * 7);
  int dlen = ND - d0; dlen = dlen < 0 ? 0 : (dlen > 7 ? 7 : dlen);
  const bool has_out = (g < NO);
  const unsigned voff = (unsigned)lane * 4u;   // shared per-lane byte offset

  __shared__ float red[NWAVE][7][64];   // 28 KB; slot 6 = window ao partials

  // ws is poisoned before every launch: zero packed r slot 0 + barrier words.
  for (int i = g * (int)blockDim.x + (int)threadIdx.x; i < RPK_STRIDE;
       i += (int)(gridDim.x * blockDim.x)) {
    rmPK[i] = 0u; rpPK[i] = 0u; rsPK[i] = 0u;
  }
  if (g <= 16 && threadIdx.x == 0) flags[g * 16] = 0u;   // root + 16 leaves

  // packed f16 weight row-slice pointers (wave-uniform -> s_load, K$-hot)
  const unsigned* wrm0b = WPK + (size_t)0 * WMAT + (size_t)n0 * (NN / 2) + m0;
  const unsigned* wrm1b = WPK + (size_t)0 * WMAT + (size_t)n1 * (NN / 2) + m0;
  const unsigned* wmp0b = WPK + (size_t)1 * WMAT + (size_t)n0 * (NN / 2) + m0;
  const unsigned* wmp1b = WPK + (size_t)1 * WMAT + (size_t)n1 * (NN / 2) + m0;
  const unsigned* wpm0b = WPK + (size_t)2 * WMAT + (size_t)n0 * (NN / 2) + m0;
  const unsigned* wpm1b = WPK + (size_t)2 * WMAT + (size_t)n1 * (NN / 2) + m0;
  const unsigned* wrp0b = WPK + (size_t)3 * WMAT + (size_t)n0 * (NN / 2) + m0;
  const unsigned* wrp1b = WPK + (size_t)3 * WMAT + (size_t)n1 * (NN / 2) + m0;
  const unsigned* wsm0b = WPK + (size_t)4 * WMAT + (size_t)n0 * (NN / 2) + m0;
  const unsigned* wsm1b = WPK + (size_t)4 * WMAT + (size_t)n1 * (NN / 2) + m0;
  const unsigned* wrs0b = WPK + (size_t)5 * WMAT + (size_t)n0 * (NN / 2) + m0;
  const unsigned* wrs1b = WPK + (size_t)5 * WMAT + (size_t)n1 * (NN / 2) + m0;
  const unsigned* wob   = WPK + (size_t)6 * WMAT
                              + (size_t)(has_out ? g : 0) * (NN / 2) + m0;
  // X-path weights stay f32 (bounds quant error to the recurrent part)
  const float* wip0 = W_in_pmd + (size_t)n0 * ND + d0;
  const float* wip1 = W_in_pmd + (size_t)n1 * ND + d0;
  const float* wis0 = W_in_s1 + (size_t)n0 * ND + d0;
  const float* wis1 = W_in_s1 + (size_t)n1 * ND + d0;

  // publish role: wave j<3 owns region j's column pair; wave 3 reduces out
  unsigned* pubPK = nullptr; float bP0 = 0.f, bP1 = 0.f;
  if (wave == 0)      { pubPK = rmPK; bP0 = b_m1[n0];  bP1 = b_m1[n1]; }
  else if (wave == 1) { pubPK = rpPK; bP0 = b_pmd[n0]; bP1 = b_pmd[n1]; }
  else if (wave == 2) { pubPK = rsPK; bP0 = b_s1[n0];  bP1 = b_s1[n1]; }
  float xP0 = 0.f, xP1 = 0.f;

  // X-part accumulators for the upcoming step (computed during barrier wait)
  float apX0 = 0.f, apX1 = 0.f, asX0 = 0.f, asX1 = 0.f;
  {
    const float* xt = XT + d0 * NB + lane;   // ti = 0
    for (int d = 0; d < dlen; ++d) {
      const float v = xt[d * NB];
      apX0 = fmaf(v, wip0[d], apX0);
      apX1 = fmaf(v, wip1[d], apX1);
      asX0 = fmaf(v, wis0[d], asX0);
      asX1 = fmaf(v, wis1[d], asX1);
    }
  }

  // one-time heavyweight sync to order init (incl. wpack results) grid-wide
  cg::this_grid().sync();

  for (int ti = 0; ti < NT; ++ti) {
    const int cur = ti & 1, nxt = cur ^ 1;
    const unsigned* bM = rmPK + cur * RPK_STRIDE + m0 * NB;   // wave-uniform
    const unsigned* bP = rpPK + cur * RPK_STRIDE + m0 * NB;
    const unsigned* bS = rsPK + cur * RPK_STRIDE + m0 * NB;

    // ---- 48 LLC-direct loads, SGPR base + imm offsets, ONE vmcnt(0) ----
    unsigned um[16], uP[16], uS[16];
    LDR(um, bM, voff);
    LDR(uP, bP, voff);
    LDR(uS, bS, voff);
    asm volatile("s_waitcnt vmcnt(0)" ::: "memory");
    __builtin_amdgcn_sched_barrier(0);   // rule #18

    float am0 = 0.f, am1 = 0.f;
    float ap0 = apX0, ap1 = apX1, as0 = asX0, as1 = asX1;

    // dot2 burn: 192 instrs, zero unpack (um/uP/uS consumed packed)
    #pragma unroll
    for (int j = 0; j < 16; ++j) {
      DOT2(am0, um[j], wrm0b[j]);
      DOT2(am1, um[j], wrm1b[j]);
      DOT2(ap0, um[j], wmp0b[j]);
      DOT2(ap1, um[j], wmp1b[j]);
    }
    #pragma unroll
    for (int j = 0; j < 16; ++j) {
      DOT2(am0, uP[j], wpm0b[j]);
      DOT2(am1, uP[j], wpm1b[j]);
      DOT2(ap0, uP[j], wrp0b[j]);
      DOT2(ap1, uP[j], wrp1b[j]);
    }
    #pragma unroll
    for (int j = 0; j < 16; ++j) {
      DOT2(am0, uS[j], wsm0b[j]);
      DOT2(am1, uS[j], wsm1b[j]);
      DOT2(as0, uS[j], wrs0b[j]);
      DOT2(as1, uS[j], wrs1b[j]);
    }

    red[wave][0][lane] = am0; red[wave][1][lane] = am1;
    red[wave][2][lane] = ap0; red[wave][3][lane] = ap1;
    red[wave][4][lane] = as0; red[wave][5][lane] = as1;
    __syncthreads();

    // publish: wave j<3 reduces its region pair -> leaky+tanh -> f16x2 pack
    // -> ONE sc store. Wave 3 stores out[ti-2] from prior window's red[.][6].
    if (wave < 3) {
      float s0 = red[0][2 * wave][lane], s1 = red[0][2 * wave + 1][lane];
      #pragma unroll
      for (int w = 1; w < NWAVE; ++w) {
        s0 += red[w][2 * wave][lane];
        s1 += red[w][2 * wave + 1][lane];
      }
      xP0 = 0.9f * xP0 + 0.1f * (s0 + bP0);
      xP1 = 0.9f * xP1 + 0.1f * (s1 + bP1);
      st_cg_u(pubPK + nxt * RPK_STRIDE + g * NB + lane,
              f2h2(tanhf(xP0), tanhf(xP1)));
    } else if (wave == 3 && has_out && ti >= 2) {
      float s = red[0][6][lane];
      #pragma unroll
      for (int w = 1; w < NWAVE; ++w) s += red[w][6][lane];
      out[(size_t)(ti - 2) * (NB * NO) + lane * NO + g] = s;
    }

    // ---- two-level barrier tree (R10-proven) ----
    __syncthreads();
    const unsigned tgtc = (unsigned)(ti + 1) * 16u;
    if (threadIdx.x == 0) {
      const unsigned old = __hip_atomic_fetch_add(
          &flags[(grp + 1) * 16], 1u, __ATOMIC_RELAXED, __HIP_MEMORY_SCOPE_AGENT);
      if (old == tgtc - 1u) {
        __hip_atomic_fetch_add(&flags[0], 1u, __ATOMIC_RELAXED,
                               __HIP_MEMORY_SCOPE_AGENT);
      }
    }

    // ---- barrier-wait window ----
    apX0 = 0.f; apX1 = 0.f; asX0 = 0.f; asX1 = 0.f;
    if (ti + 1 < NT) {
      const float* xt = XT + (size_t)(ti + 1) * ND * NB + d0 * NB + lane;
      for (int d = 0; d < dlen; ++d) {
        const float v = xt[d * NB];
        apX0 = fmaf(v, wip0[d], apX0);
        apX1 = fmaf(v, wip1[d], apX1);
        asX0 = fmaf(v, wis0[d], asX0);
        asX1 = fmaf(v, wis1[d], asX1);
      }
    }
    if (has_out) {
      float ao = 0.f;
      #pragma unroll
      for (int j = 0; j < 16; ++j) DOT2(ao, um[j], wob[j]);
      red[wave][6][lane] = ao;
    }

    if (threadIdx.x == 0) {
      while (__hip_atomic_load(&flags[0], __ATOMIC_RELAXED,
                               __HIP_MEMORY_SCOPE_AGENT) < tgtc)
        __builtin_amdgcn_s_sleep(1);
      // no acquire fence: r reads are LLC-direct (R9-proven)
    }
    __syncthreads();
  }

  // epilogue (per-WG; has_out uniform within WG so barriers are safe):
  if (has_out) {
    if (wave == 3) {
      float s = red[0][6][lane];
      #pragma unroll
      for (int w = 1; w < NWAVE; ++w) s += red[w][6][lane];
      out[(size_t)(NT - 2) * (NB * NO) + lane * NO + g] = s;
    }
    __syncthreads();
    const unsigned* rmP = rmPK + (NT & 1) * RPK_STRIDE + m0 * NB + lane;
    unsigned um[16];
    #pragma unroll
    for (int k2 = 0; k2 < 16; ++k2) LD_SC(um[k2], rmP + k2 * NB);
    asm volatile("s_waitcnt vmcnt(0)" ::: "memory");
    __builtin_amdgcn_sched_barrier(0);
    float ao = 0.f;
    #pragma unroll
    for (int j = 0; j < 16; ++j) DOT2(ao, um[j], wob[j]);
    red[wave][6][lane] = ao;
    __syncthreads();
    if (wave == 3) {
      float t = red[0][6][lane];
      #pragma unroll
      for (int w = 1; w < NWAVE; ++w) t += red[w][6][lane];
      out[(size_t)(NT - 1) * (NB * NO) + lane * NO + g] = t;
    }
  }
}

extern "C" void kernel_launch(void* const* d_in, const int* in_sizes, int n_in,
                              void* d_out, int out_size, void* d_ws, size_t ws_size,
                              hipStream_t stream) {
  (void)in_sizes; (void)n_in; (void)out_size; (void)ws_size;
  const float* X         = (const float*)d_in[0];
  const float* W_rec_m1  = (const float*)d_in[1];
  const float* W_rec_pmd = (const float*)d_in[2];
  const float* W_rec_s1  = (const float*)d_in[3];
  const float* b_m1      = (const float*)d_in[4];
  const float* b_pmd     = (const float*)d_in[5];
  const float* b_s1      = (const float*)d_in[6];
  const float* W_pmd_m1  = (const float*)d_in[7];
  const float* W_s1_m1   = (const float*)d_in[8];
  const float* W_m1_pmd  = (const float*)d_in[9];
  const float* W_in_pmd  = (const float*)d_in[10];
  const float* W_in_s1   = (const float*)d_in[11];
  const float* W_out     = (const float*)d_in[12];
  float* out = (float*)d_out;

  float* wsf = (float*)d_ws;
  const float* XT = wsf + XT_OFF;
  float* XTw   = wsf + XT_OFF;
  unsigned* rmPK = (unsigned*)(wsf + RM_OFF);
  unsigned* rpPK = (unsigned*)(wsf + RP_OFF);
  unsigned* rsPK = (unsigned*)(wsf + RS_OFF);
  unsigned* flags = (unsigned*)(wsf + FLAG_OFF);
  unsigned* WPK   = (unsigned*)(wsf + WPK_OFF);

  xpose_kernel<<<NT, 256, 0, stream>>>(X, XTw);
  wpack_kernel<<<6 * NN + NO, 256, 0, stream>>>(
      W_rec_m1, W_m1_pmd, W_pmd_m1, W_rec_pmd, W_s1_m1, W_rec_s1, W_out, WPK);

  const unsigned* WPKc = WPK;
  void* args[12];
  args[0]  = (void*)&XT;
  args[1]  = (void*)&rmPK;  args[2]  = (void*)&rpPK; args[3]  = (void*)&rsPK;
  args[4]  = (void*)&WPKc;
  args[5]  = (void*)&b_m1;  args[6]  = (void*)&b_pmd; args[7]  = (void*)&b_s1;
  args[8]  = (void*)&W_in_pmd; args[9] = (void*)&W_in_s1;
  args[10] = (void*)&out;
  args[11] = (void*)&flags;
  hipLaunchCooperativeKernel((const void*)rnn_kernel, dim3(NWG), dim3(1024), args, 0, stream);
}